// Round 12
// baseline (59.661 us; speedup 1.0000x reference)
//
#include <hip/hip_runtime.h>

#define NROWS 65536
#define DIM   64
#define NE    512

// d_out is FLOAT32: [ z_q (4194304) | indices-as-float (65536) | loss (1) ]
// All scratch lives in d_ws (>= 142 KB; observed ~256 MB):
#define WS_PRESPLIT 0        // 512 rows x 256B: (-2e)_hi swizzled | (-2e)_lo at +128
#define WS_PREY     131072   // 512 x 16B: (ynorm_hi, ynorm_lo, 0...)
#define WS_YNORM    139264   // 512 x f32 np-pairwise ||e||^2
#define WS_ACC      141312   // u64 fixed-point loss accumulator
#define WS_TICKET   141320   // u32 completion ticket

typedef __attribute__((ext_vector_type(8)))  short bf16x8;
typedef __attribute__((ext_vector_type(16))) float f32x16;

static __device__ __forceinline__ unsigned short bf16rne(float x) {
    unsigned int u = __float_as_uint(x);
    u += 0x7FFFu + ((u >> 16) & 1u);            // RNE (finite inputs only)
    return (unsigned short)(u >> 16);
}
static __device__ __forceinline__ float bf16tof(unsigned short h) {
    return __uint_as_float(((unsigned int)h) << 16);
}

// K0: one-time codebook prep (512 rows, 2 blocks) + zero loss acc/ticket.
__global__ __launch_bounds__(256) void vq_prep(
    const float* __restrict__ ew, char* ws)
{
    const int r = blockIdx.x * 256 + threadIdx.x;     // 0..511
    if (r == 0) {
        *(unsigned long long*)(ws + WS_ACC)    = 0ull;
        *(unsigned long long*)(ws + WS_TICKET) = 0ull;
    }
    float a[64];
    const float4* src = (const float4*)(ew + (size_t)r * DIM);
    #pragma unroll
    for (int q = 0; q < 16; ++q) {
        float4 v = src[q];
        a[q*4+0]=v.x; a[q*4+1]=v.y; a[q*4+2]=v.z; a[q*4+3]=v.w;
    }
    // numpy-pairwise ||e||^2 (exact np f32 order)
    float rc[8];
    #pragma unroll
    for (int j = 0; j < 8; ++j) rc[j] = __fmul_rn(a[j], a[j]);
    #pragma unroll
    for (int i = 8; i < 64; i += 8)
        #pragma unroll
        for (int j = 0; j < 8; ++j)
            rc[j] = __fadd_rn(rc[j], __fmul_rn(a[i+j], a[i+j]));
    float Y = __fadd_rn(__fadd_rn(__fadd_rn(rc[0],rc[1]),__fadd_rn(rc[2],rc[3])),
                        __fadd_rn(__fadd_rn(rc[4],rc[5]),__fadd_rn(rc[6],rc[7])));
    ((float*)(ws + WS_YNORM))[r] = Y;
    unsigned short ynh = bf16rne(Y);
    unsigned short ynl = bf16rne(Y - bf16tof(ynh));
    bf16x8 py = {};
    py[0] = (short)ynh; py[1] = (short)ynl;
    *(bf16x8*)(ws + WS_PREY + r*16) = py;
    const int sw = (r & 7) << 4;
    char* base = ws + WS_PRESPLIT + (size_t)r * 256;
    #pragma unroll
    for (int c = 0; c < 8; ++c) {
        bf16x8 h, l;
        #pragma unroll
        for (int j = 0; j < 8; ++j) {
            float x = -2.0f * a[c*8+j];
            unsigned short hb = bf16rne(x);
            h[j] = (short)hb;
            l[j] = (short)bf16rne(x - bf16tof(hb));
        }
        int off = (c*16) ^ sw;
        *(bf16x8*)(base + off) = h;
        *(bf16x8*)(base + off + 128) = l;
    }
}

// K1: fused MFMA ranking + in-block near-tie rescan + index/z_q write + loss.
// 512 blocks x 4 waves; each block owns 128 rows.
__global__ __launch_bounds__(256) void vq_fused(
    const float* __restrict__ z, const float* __restrict__ ew,
    char* ws, float* out)
{
    __shared__ __align__(16) char lds[65536];     // half preSplit (A tiles)
    __shared__ __align__(16) char ldsY[8192];     // preY fragments
    __shared__ int   rwin[128];
    __shared__ float rdist[128];
    __shared__ float rX[128];
    __shared__ unsigned int flagbits[4];
    __shared__ float rd4[4];
    __shared__ int   ri4[4];
    __shared__ float wred[4];

    const int tid  = threadIdx.x;
    const int lane = tid & 63;
    const int w    = tid >> 6;
    const int hh   = lane >> 5;
    const int l31  = lane & 31;
    const int R0   = blockIdx.x * 128;
    const int zrow = R0 + w * 32 + l31;

    if (tid < 4) flagbits[tid] = 0;

    // ---- z fragments (split-bf16) + f32 sum-sq; B layout: n=lane&31, k=8*hh+j ----
    bf16x8 zh[4], zl[4];
    float xacc = 0.f;
    {
        const float* zp = z + (size_t)zrow * DIM + hh * 8;
        #pragma unroll
        for (int kt = 0; kt < 4; ++kt) {
            float4 p0 = *(const float4*)(zp + kt*16);
            float4 p1 = *(const float4*)(zp + kt*16 + 4);
            float a[8] = {p0.x,p0.y,p0.z,p0.w,p1.x,p1.y,p1.z,p1.w};
            bf16x8 hv, lv;
            #pragma unroll
            for (int j = 0; j < 8; ++j) {
                unsigned short hb = bf16rne(a[j]);
                hv[j] = (short)hb;
                lv[j] = (short)bf16rne(a[j] - bf16tof(hb));
                xacc  = fmaf(a[j], a[j], xacc);
            }
            zh[kt] = hv; zl[kt] = lv;
        }
    }

    #pragma unroll
    for (int i = 0; i < 2; ++i)
        *(float4*)(ldsY + (tid + 256*i)*16) =
            *(const float4*)(ws + WS_PREY + (tid + 256*i)*16);

    const bf16x8 zero8 = {};
    bf16x8 bones = {};
    if (hh == 0) { bones[0] = (short)0x3F80; bones[1] = (short)0x3F80; }

    float d1 = 3.4e38f, d2 = 3.4e38f;
    int   i1 = 0;

    for (int h = 0; h < 2; ++h) {
        __syncthreads();
        #pragma unroll
        for (int i = 0; i < 16; ++i)
            *(float4*)(lds + tid*16 + i*4096) =
                *(const float4*)(ws + WS_PRESPLIT + h*65536 + tid*16 + i*4096);
        __syncthreads();

        for (int t = 0; t < 8; ++t) {
            const int   arow  = t*32 + l31;
            const char* abase = lds + arow*256;
            const int   sw    = (arow & 7) << 4;
            f32x16 acc;
            #pragma unroll
            for (int g = 0; g < 16; ++g) acc[g] = 0.f;
            #pragma unroll
            for (int kt = 0; kt < 4; ++kt) {
                const int kb = (kt*32 + hh*16) ^ sw;
                bf16x8 ah = *(const bf16x8*)(abase + kb);
                bf16x8 al = *(const bf16x8*)(abase + kb + 128);
                acc = __builtin_amdgcn_mfma_f32_32x32x16_bf16(ah, zh[kt], acc, 0,0,0);
                acc = __builtin_amdgcn_mfma_f32_32x32x16_bf16(ah, zl[kt], acc, 0,0,0);
                acc = __builtin_amdgcn_mfma_f32_32x32x16_bf16(al, zh[kt], acc, 0,0,0);
            }
            bf16x8 ay = *(const bf16x8*)(ldsY + (h*256 + t*32 + l31)*16);
            if (hh) ay = zero8;
            acc = __builtin_amdgcn_mfma_f32_32x32x16_bf16(ay, bones, acc, 0,0,0);

            const int ebase = h*256 + t*32 + 4*hh;
            #pragma unroll
            for (int g = 0; g < 16; ++g) {
                float d = acc[g];
                int   e = ebase + (g & 3) + 8*(g >> 2);
                d2 = fminf(fmaxf(d, d1), d2);
                bool bt = d < d1;
                i1 = bt ? e : i1;
                d1 = fminf(d, d1);
            }
        }
    }

    // ---- merge half-lane pools; per-row flag; deposit row info ----
    float od1 = __shfl_xor(d1, 32, 64);
    int   oi1 = __shfl_xor(i1, 32, 64);
    float od2 = __shfl_xor(d2, 32, 64);
    bool  oth = (od1 < d1) || (od1 == d1 && oi1 < i1);
    int   wi  = oth ? oi1 : i1;
    float s1  = fminf(d1, od1);
    float s2  = fminf(fmaxf(d1, od1), fminf(d2, od2));
    float Xf  = xacc + __shfl_xor(xacc, 32, 64);
    float Xs  = Xf + 1e-3f;
    float ue  = __uint_as_float(__float_as_uint(Xs) & 0x7F800000u) * 1.1920929e-7f;
    bool  flag = (s2 - s1) < (2.0f * ue + 2e-6f);

    if (hh == 0) {
        int r = w*32 + l31;
        rwin[r]  = wi;
        rdist[r] = s1;            // approx d - X (ynorm - 2 z.e)
        rX[r]    = Xf;            // + X added in loss epilogue
        if (flag) atomicOr(&flagbits[r >> 5], 1u << (r & 31));
    }
    __syncthreads();

    // ---- in-block rescan of flagged rows (np-f32 exact, block-parallel) ----
    const float* yn = (const float*)(ws + WS_YNORM);
    for (int wb = 0; wb < 4; ++wb) {
        unsigned bits = flagbits[wb];
        while (bits) {
            int r = wb*32 + __ffs(bits) - 1;
            bits &= bits - 1;
            const float* zq = z + (size_t)(R0 + r) * DIM;
            float zr[64];
            #pragma unroll
            for (int q = 0; q < 16; ++q) {
                float4 v = *(const float4*)(zq + q*4);
                zr[q*4+0]=v.x; zr[q*4+1]=v.y; zr[q*4+2]=v.z; zr[q*4+3]=v.w;
            }
            float rc[8];
            #pragma unroll
            for (int j = 0; j < 8; ++j) rc[j] = __fmul_rn(zr[j], zr[j]);
            #pragma unroll
            for (int i = 8; i < 64; i += 8)
                #pragma unroll
                for (int j = 0; j < 8; ++j)
                    rc[j] = __fadd_rn(rc[j], __fmul_rn(zr[i+j], zr[i+j]));
            float xn = __fadd_rn(__fadd_rn(__fadd_rn(rc[0],rc[1]),__fadd_rn(rc[2],rc[3])),
                                 __fadd_rn(__fadd_rn(rc[4],rc[5]),__fadd_rn(rc[6],rc[7])));
            float bd = 3.4e38f; int bi = NE;
            #pragma unroll
            for (int half = 0; half < 2; ++half) {
                int e = tid + half * 256;
                const float* ep = ew + (size_t)e * DIM;
                double m0 = 0.0, m1 = 0.0, m2 = 0.0, m3 = 0.0;
                #pragma unroll
                for (int q = 0; q < 16; ++q) {
                    float4 ev = *(const float4*)(ep + q*4);
                    m0 = fma((double)zr[q*4+0], (double)ev.x, m0);
                    m1 = fma((double)zr[q*4+1], (double)ev.y, m1);
                    m2 = fma((double)zr[q*4+2], (double)ev.z, m2);
                    m3 = fma((double)zr[q*4+3], (double)ev.w, m3);
                }
                double m = (m0 + m1) + (m2 + m3);
                float W = __fadd_rn(xn, yn[e]);
                float d = __fadd_rn(W, -(2.0f * (float)m));
                if (d < bd || (d == bd && e < bi)) { bd = d; bi = e; }
            }
            #pragma unroll
            for (int off = 32; off >= 1; off >>= 1) {
                float od = __shfl_xor(bd, off, 64);
                int   oi = __shfl_xor(bi, off, 64);
                if (od < bd || (od == bd && oi < bi)) { bd = od; bi = oi; }
            }
            if (lane == 0) { rd4[w] = bd; ri4[w] = bi; }
            __syncthreads();
            if (tid == 0) {
                float fd = rd4[0]; int fi = ri4[0];
                #pragma unroll
                for (int k = 1; k < 4; ++k)
                    if (rd4[k] < fd || (rd4[k] == fd && ri4[k] < fi)) { fd = rd4[k]; fi = ri4[k]; }
                rwin[r]  = fi;
                rdist[r] = fd;    // FULL np distance (includes X)
                rX[r]    = 0.f;   // avoid double-counting X in loss epilogue
            }
            __syncthreads();
        }
    }

    // ---- index write (coalesced 128 floats) ----
    if (tid < 128)
        out[(size_t)NROWS*DIM + R0 + tid] = (float)rwin[tid];

    // ---- z_q write: 128 rows x 16 float4 = 2048 float4 over 256 threads ----
    #pragma unroll
    for (int i = 0; i < 8; ++i) {
        int f4  = tid + 256 * i;          // 0..2047
        int row = f4 >> 4;                // 0..127
        int c4  = f4 & 15;
        float4 v = *(const float4*)(ew + (size_t)rwin[row] * DIM + c4 * 4);
        *(float4*)(out + (size_t)R0 * DIM + (size_t)f4 * 4) = v;
    }

    // ---- loss: term = X + d per row; block reduce; fixed-point u64 atomic ----
    float term = (tid < 128) ? (rX[tid] + rdist[tid]) : 0.f;
    #pragma unroll
    for (int off = 32; off >= 1; off >>= 1) term += __shfl_xor(term, off, 64);
    if (lane == 0) wred[w] = term;
    __syncthreads();
    if (tid == 0) {
        float part = wred[0] + wred[1] + wred[2] + wred[3];
        unsigned long long q =
            (unsigned long long)((double)part * 268435456.0 + 0.5);
        atomicAdd((unsigned long long*)(ws + WS_ACC), q);
        __threadfence();
        unsigned int tk = atomicAdd((unsigned int*)(ws + WS_TICKET), 1u);
        if (tk == 511u) {
            unsigned long long tot =
                atomicAdd((unsigned long long*)(ws + WS_ACC), 0ull);
            out[(size_t)NROWS*DIM + NROWS] =
                (float)(0.25 * ((double)tot / 268435456.0)
                        / (double)((size_t)NROWS * DIM));
        }
    }
}

extern "C" void kernel_launch(void* const* d_in, const int* in_sizes, int n_in,
                              void* d_out, int out_size, void* d_ws, size_t ws_size,
                              hipStream_t stream) {
    const float* z  = (const float*)d_in[0];
    const float* ew = (const float*)d_in[1];
    float* out = (float*)d_out;
    char*  ws  = (char*)d_ws;    // ~142 KB used; every byte rewritten each call
    vq_prep <<<2,   256, 0, stream>>>(ew, ws);
    vq_fused<<<512, 256, 0, stream>>>(z, ew, ws, out);
}